// Round 6
// baseline (58.626 us; speedup 1.0000x reference)
//
#include <hip/hip_runtime.h>
#include <hip/hip_fp16.h>
#include <math.h>

#define NRAYS 16384
#define NPTS  256
#define GS    160
#define GS3   (GS*GS*GS)

// ACT_SHIFT = log(1/(1-1e-6) - 1) computed in double precision
#define ACT_SHIFT (-13.815509557963774f)
#define LOG2E     (1.4426950408889634f)

__device__ __forceinline__ unsigned int pack2h(float a, float b) {
    __half2 h = __halves2half2(__float2half_rn(a), __float2half_rn(b));
    return *reinterpret_cast<unsigned int*>(&h);
}

// splat float -> half2 with a single v_cvt_pkrtz_f16_f32
__device__ __forceinline__ __half2 splat_h2(float x) {
    auto v = __builtin_amdgcn_cvt_pkrtz(x, x);   // <2 x half>
    return *reinterpret_cast<__half2*>(&v);
}

__device__ __forceinline__ __half2 as_h2(unsigned int u) {
    return *reinterpret_cast<__half2*>(&u);
}

// ---- repack: SoA f32 grids -> fp16 AoS y-pair grid ----
// entry[z][y][x] (16B) = {d,r}(z,y,x), {g,b}(z,y,x), {d,r}(z,y+1,x), {g,b}(z,y+1,x)
// Sampler reads entries (z,y0,x0) and (z,y0,x0+1): adjacent 16B -> same 64B line 3/4
// of the time, so lines/point = 2*1.25 = 2.5 (was 4 with x-pair layout).
__global__ __launch_bounds__(256)
void repack_ypairs_kernel(const float* __restrict__ dgrid,
                          const float* __restrict__ cgrid,
                          uint4* __restrict__ out)
{
    const int i = blockIdx.x * 256 + threadIdx.x;
    if (i >= GS3) return;
    const int y  = (i / GS) % GS;
    const int iy = (y < GS - 1) ? i + GS : i;   // (z, y+1, x); dup at y edge (never sampled)

    uint4 v;
    v.x = pack2h(dgrid[i],         cgrid[i]);
    v.y = pack2h(cgrid[GS3 + i],   cgrid[2*GS3 + i]);
    v.z = pack2h(dgrid[iy],        cgrid[iy]);
    v.w = pack2h(cgrid[GS3 + iy],  cgrid[2*GS3 + iy]);
    out[i] = v;
}

// ---- sample: 4 gathers (2.5 lines)/point, packed-fp16 interp, native transcendentals ----
__global__ __launch_bounds__(256)
void sample_ypairs_kernel(const float* __restrict__ origins,
                          const float* __restrict__ directions,
                          const float* __restrict__ lengths,
                          const uint4* __restrict__ grid,
                          float* __restrict__ out_density,
                          float* __restrict__ out_color)
{
    const int r = blockIdx.x;
    const int p = threadIdx.x;
    const int idx = r * NPTS + p;

    const float t  = lengths[idx];
    const float ox = origins[3*r+0], oy = origins[3*r+1], oz = origins[3*r+2];
    const float dx = directions[3*r+0], dy = directions[3*r+1], dz = directions[3*r+2];
    const float interval = sqrtf(dx*dx + dy*dy + dz*dz);

    const float x = ox + dx*t;
    const float y = oy + dy*t;
    const float z = oz + dz*t;

    // map [-1,1] -> [0, GS-1] (align_corners=True)
    const float half_sm1 = 0.5f * (float)(GS - 1);
    const float px = (x + 1.0f) * half_sm1;
    const float py = (y + 1.0f) * half_sm1;
    const float pz = (z + 1.0f) * half_sm1;

    const float fx = floorf(px), fy = floorf(py), fz = floorf(pz);
    const float wx1 = px - fx, wy1 = py - fy, wz1 = pz - fz;
    const float wx0 = 1.0f - wx1, wy0 = 1.0f - wy1, wz0 = 1.0f - wz1;

    int x0 = (int)fx, y0 = (int)fy, z0 = (int)fz;
    x0 = min(max(x0, 0), GS-2);
    y0 = min(max(y0, 0), GS-2);
    z0 = min(max(z0, 0), GS-2);

    const int i0 = ((z0  )*GS + y0)*GS + x0;   // entry (z0, y0, x0)
    const int i1 = ((z0+1)*GS + y0)*GS + x0;   // entry (z1, y0, x0)

    // issue all 4 16B gathers before consuming (max MLP)
    const uint4 e00 = grid[i0];        // z0, x0  (rows y0, y0+1)
    const uint4 e01 = grid[i0 + 1];    // z0, x1
    const uint4 e10 = grid[i1];        // z1, x0
    const uint4 e11 = grid[i1 + 1];    // z1, x1

    // 8 corner weights, splatted to half2 (computed while loads are in flight)
    const float wz0y0 = wz0*wy0, wz0y1 = wz0*wy1;
    const float wz1y0 = wz1*wy0, wz1y1 = wz1*wy1;
    const __half2 w000 = splat_h2(wz0y0*wx0), w001 = splat_h2(wz0y0*wx1);
    const __half2 w010 = splat_h2(wz0y1*wx0), w011 = splat_h2(wz0y1*wx1);
    const __half2 w100 = splat_h2(wz1y0*wx0), w101 = splat_h2(wz1y0*wx1);
    const __half2 w110 = splat_h2(wz1y1*wx0), w111 = splat_h2(wz1y1*wx1);

    // packed-fp16 trilinear accumulate: acc_dr = (density,red), acc_gb = (green,blue)
    __half2 acc_dr = splat_h2(0.0f);
    __half2 acc_gb = acc_dr;
    acc_dr = __hfma2(as_h2(e00.x), w000, acc_dr);  // (z0,y0,x0)
    acc_gb = __hfma2(as_h2(e00.y), w000, acc_gb);
    acc_dr = __hfma2(as_h2(e00.z), w010, acc_dr);  // (z0,y1,x0)
    acc_gb = __hfma2(as_h2(e00.w), w010, acc_gb);
    acc_dr = __hfma2(as_h2(e01.x), w001, acc_dr);  // (z0,y0,x1)
    acc_gb = __hfma2(as_h2(e01.y), w001, acc_gb);
    acc_dr = __hfma2(as_h2(e01.z), w011, acc_dr);  // (z0,y1,x1)
    acc_gb = __hfma2(as_h2(e01.w), w011, acc_gb);
    acc_dr = __hfma2(as_h2(e10.x), w100, acc_dr);  // (z1,y0,x0)
    acc_gb = __hfma2(as_h2(e10.y), w100, acc_gb);
    acc_dr = __hfma2(as_h2(e10.z), w110, acc_dr);  // (z1,y1,x0)
    acc_gb = __hfma2(as_h2(e10.w), w110, acc_gb);
    acc_dr = __hfma2(as_h2(e11.x), w101, acc_dr);  // (z1,y0,x1)
    acc_gb = __hfma2(as_h2(e11.y), w101, acc_gb);
    acc_dr = __hfma2(as_h2(e11.z), w111, acc_dr);  // (z1,y1,x1)
    acc_gb = __hfma2(as_h2(e11.w), w111, acc_gb);

    const float s0 = __low2float(acc_dr);
    const float s1 = __high2float(acc_dr);
    const float s2 = __low2float(acc_gb);
    const float s3 = __high2float(acc_gb);

    // density = 1 - (1+e^a)^(-interval) = 1 - 2^(-interval * log2(1 + 2^(a*log2e)))
    const float a  = s0 + ACT_SHIFT;
    const float ea = __builtin_amdgcn_exp2f(LOG2E * a);
    const float L  = __builtin_amdgcn_logf(1.0f + ea);
    out_density[idx] = 1.0f - __builtin_amdgcn_exp2f(-interval * L);

    // sigmoid via native exp2 + rcp
    const float e1 = __builtin_amdgcn_exp2f(-LOG2E * s1);
    const float e2 = __builtin_amdgcn_exp2f(-LOG2E * s2);
    const float e3 = __builtin_amdgcn_exp2f(-LOG2E * s3);
    out_color[idx*3 + 0] = __builtin_amdgcn_rcpf(1.0f + e1);
    out_color[idx*3 + 1] = __builtin_amdgcn_rcpf(1.0f + e2);
    out_color[idx*3 + 2] = __builtin_amdgcn_rcpf(1.0f + e3);
}

// ---------------- fallback: direct SoA sampling (round-2 kernel) ----------------
__device__ __forceinline__ float2 ld2(const float* p) {
    return *reinterpret_cast<const float2*>(p);
}

__global__ __launch_bounds__(256)
void dvgo_render_kernel(const float* __restrict__ origins,
                        const float* __restrict__ directions,
                        const float* __restrict__ lengths,
                        const float* __restrict__ dgrid,
                        const float* __restrict__ cgrid,
                        float* __restrict__ out_density,
                        float* __restrict__ out_color)
{
    const int r = blockIdx.x;
    const int p = threadIdx.x;
    const int idx = r * NPTS + p;

    const float t  = lengths[idx];
    const float ox = origins[3*r+0], oy = origins[3*r+1], oz = origins[3*r+2];
    const float dx = directions[3*r+0], dy = directions[3*r+1], dz = directions[3*r+2];
    const float interval = sqrtf(dx*dx + dy*dy + dz*dz);

    const float x = ox + dx*t;
    const float y = oy + dy*t;
    const float z = oz + dz*t;

    const float half_sm1 = 0.5f * (float)(GS - 1);
    const float px = (x + 1.0f) * half_sm1;
    const float py = (y + 1.0f) * half_sm1;
    const float pz = (z + 1.0f) * half_sm1;

    const float fx = floorf(px), fy = floorf(py), fz = floorf(pz);
    const float wx1 = px - fx, wy1 = py - fy, wz1 = pz - fz;
    const float wx0 = 1.0f - wx1, wy0 = 1.0f - wy1, wz0 = 1.0f - wz1;

    int x0 = (int)fx, y0 = (int)fy, z0 = (int)fz;
    x0 = min(max(x0, 0), GS-2);
    y0 = min(max(y0, 0), GS-2);
    z0 = min(max(z0, 0), GS-2);

    int rows[4];
    rows[0] = ((z0  )*GS + y0  )*GS + x0;
    rows[1] = ((z0  )*GS + y0+1)*GS + x0;
    rows[2] = ((z0+1)*GS + y0  )*GS + x0;
    rows[3] = ((z0+1)*GS + y0+1)*GS + x0;

    const float* bases[4] = {dgrid, cgrid, cgrid + GS3, cgrid + 2*GS3};

    float2 v[4][4];
    #pragma unroll
    for (int ch = 0; ch < 4; ++ch)
        #pragma unroll
        for (int rr = 0; rr < 4; ++rr)
            v[ch][rr] = ld2(bases[ch] + rows[rr]);

    float rw[4];
    rw[0] = wz0*wy0; rw[1] = wz0*wy1; rw[2] = wz1*wy0; rw[3] = wz1*wy1;

    float s[4];
    #pragma unroll
    for (int ch = 0; ch < 4; ++ch) {
        float acc = 0.0f;
        #pragma unroll
        for (int rr = 0; rr < 4; ++rr)
            acc = fmaf(rw[rr], fmaf(v[ch][rr].x, wx0, v[ch][rr].y * wx1), acc);
        s[ch] = acc;
    }

    const float a  = s[0] + ACT_SHIFT;
    const float sp = (a > 20.0f) ? a : log1pf(__expf(a));
    out_density[idx] = 1.0f - __expf(-interval * sp);

    #pragma unroll
    for (int c = 0; c < 3; ++c)
        out_color[idx*3 + c] = 1.0f / (1.0f + __expf(-s[c+1]));
}

extern "C" void kernel_launch(void* const* d_in, const int* in_sizes, int n_in,
                              void* d_out, int out_size, void* d_ws, size_t ws_size,
                              hipStream_t stream) {
    const float* origins    = (const float*)d_in[0];
    const float* directions = (const float*)d_in[1];
    const float* lengths    = (const float*)d_in[2];
    const float* dgrid      = (const float*)d_in[3];
    const float* cgrid      = (const float*)d_in[4];

    float* out_density = (float*)d_out;               // [R, P, 1]
    float* out_color   = (float*)d_out + NRAYS*NPTS;  // [R, P, 3]

    if (ws_size >= (size_t)GS3 * sizeof(uint4)) {
        uint4* pairs = (uint4*)d_ws;
        repack_ypairs_kernel<<<(GS3 + 255) / 256, 256, 0, stream>>>(dgrid, cgrid, pairs);
        sample_ypairs_kernel<<<NRAYS, NPTS, 0, stream>>>(
            origins, directions, lengths, pairs, out_density, out_color);
    } else {
        dvgo_render_kernel<<<NRAYS, NPTS, 0, stream>>>(
            origins, directions, lengths, dgrid, cgrid, out_density, out_color);
    }
}